// Round 9
// baseline (1487.899 us; speedup 1.0000x reference)
//
#include <hip/hip_runtime.h>
#include <hip/hip_cooperative_groups.h>
#include <cstdint>
#include <cstddef>

namespace cg = cooperative_groups;

#define NN 50000
#define MP 50048   // rows padded to multiple of 64
#define NE 800000
#define NB 196     // buckets of 256 nodes (dst >> 8)
#define BCAP 5120  // per-bucket edge capacity (mean 4082, sigma ~64)
#define EPB 4096   // edges per bin block
#define NT 782     // node tiles (MP/64)

typedef __attribute__((ext_vector_type(8))) _Float16 half8;
typedef __attribute__((ext_vector_type(4))) float f32x4;

__device__ inline unsigned short f2h(float f){
  _Float16 h = (_Float16)f;
  return *(unsigned short*)&h;
}
__device__ inline float h2f(unsigned u){
  _Float16 h = *(_Float16*)&u;
  return (float)h;
}
__device__ inline float fast_rcp(float x){ return __builtin_amdgcn_rcpf(x); }
__device__ inline float sigm(float z){ return fast_rcp(1.f + __expf(-z)); }
__device__ inline float tanh_f(float z){
  z = fminf(fmaxf(z, -15.f), 15.f);
  float e = __expf(2.f * z);
  return 1.f - 2.f * fast_rcp(e + 1.f);
}

// LDS 64x64 fp16 tile, XOR-swizzled in 16B chunks: chunk ^= (row&7)
__device__ inline half8 lds_frag(const _Float16* tile, int row, int kb){
  return *(const half8*)(tile + row * 64 + ((((kb) >> 3) ^ (row & 7)) << 3));
}
__device__ inline void lds_put(_Float16* tile, int row, int col, float v){
  tile[row * 64 + ((((col) >> 3) ^ (row & 7)) << 3) + (col & 7)] = (_Float16)v;
}
__device__ inline half8 cvt8(float4 a, float4 b){
  half8 h;
  h[0] = (_Float16)a.x; h[1] = (_Float16)a.y; h[2] = (_Float16)a.z; h[3] = (_Float16)a.w;
  h[4] = (_Float16)b.x; h[5] = (_Float16)b.y; h[6] = (_Float16)b.z; h[7] = (_Float16)b.w;
  return h;
}

union SmU {
  struct { unsigned buf[EPB]; unsigned char sb[EPB]; int lh[256]; int lex[256]; int lc[256]; int gb[256]; } bin;
  struct { unsigned short sbuf[BCAP]; int lh[256]; int lex[256]; int lc[256]; int s_base; int s_cnt; } csr;
  _Float16 tile[64 * 64];
};

struct Args {
  const int* src; const int* dst;
  int* bcnt; unsigned* bedg;
  const float* W_in; const float* msg_W; const float* rs_W; const float* up_W; const float* cd_W;
  _Float16* wpk;
  unsigned short* srcs; int* offsets;
  const float* x;
  const float* b_in; const float* msg_b; const float* rs_b; const float* up_b; const float* cd_b;
  float* state_f;
  _Float16* msg0; _Float16* msg1; _Float16* agg;
  float* out;
};

// ===================== phase bodies (device inline) =====================
__device__ inline void bin_body(SmU& sm, int u, const Args& a) {
  const int tid = threadIdx.x;
  const int e0 = u * EPB;
  const int tot = min(EPB, NE - e0);
  sm.bin.lh[tid] = 0;
  __syncthreads();
  for (int i = tid; i < tot; i += 256) {
    int b = a.dst[e0 + i] >> 8;
    atomicAdd(&sm.bin.lh[b], 1);
  }
  __syncthreads();
  int cnt = sm.bin.lh[tid];
  int val = cnt;
#pragma unroll
  for (int off = 1; off < 256; off <<= 1) {
    int t = (tid >= off) ? sm.bin.lh[tid - off] : 0;
    __syncthreads();
    val += t;
    sm.bin.lh[tid] = val;
    __syncthreads();
  }
  int excl = val - cnt;
  sm.bin.lex[tid] = excl;
  sm.bin.lc[tid] = excl;
  if (tid < NB && cnt > 0) sm.bin.gb[tid] = atomicAdd(&a.bcnt[tid], cnt);
  else sm.bin.gb[tid] = 0;
  __syncthreads();
  for (int i = tid; i < tot; i += 256) {
    int s = a.src[e0 + i], d = a.dst[e0 + i];
    int b = d >> 8;
    int p = atomicAdd(&sm.bin.lc[b], 1);
    sm.bin.buf[p] = (unsigned)s | ((unsigned)(d & 255) << 16);
    sm.bin.sb[p] = (unsigned char)b;
  }
  __syncthreads();
  for (int i = tid; i < tot; i += 256) {
    int b = sm.bin.sb[i];
    int gpos = sm.bin.gb[b] + (i - sm.bin.lex[b]);
    if (gpos < BCAP) a.bedg[(size_t)b * BCAP + gpos] = sm.bin.buf[i];
  }
  __syncthreads();
}

__device__ inline void pack_body(int ub, const Args& a) {
  const int tid = threadIdx.x;
  int fb = ub * 4 + (tid >> 6);
  int l = tid & 63;
  if (fb < 176) {
    const float* W; int KT, fi;
    if (fb < 8)        { W = a.W_in;                            KT = 2; fi = fb; }
    else if (fb < 32)  { int r = (fb - 8) >> 3;   W = a.msg_W + (size_t)r * 64 * 64;  KT = 2; fi = (fb - 8) & 7; }
    else if (fb < 80)  { int r = (fb - 32) >> 4;  W = a.rs_W + (size_t)r * 128 * 64;  KT = 4; fi = (fb - 32) & 15; }
    else if (fb < 128) { int r = (fb - 80) >> 4;  W = a.up_W + (size_t)r * 128 * 64;  KT = 4; fi = (fb - 80) & 15; }
    else               { int r = (fb - 128) >> 4; W = a.cd_W + (size_t)r * 128 * 64;  KT = 4; fi = (fb - 128) & 15; }
    int nt = fi / KT, kt = fi % KT;
    int rb = kt * 32 + (l >> 4) * 8;
    int col = nt * 16 + (l & 15);
    half8 p;
#pragma unroll
    for (int i = 0; i < 8; ++i) p[i] = (_Float16)W[(size_t)(rb + i) * 64 + col];
    *(half8*)(a.wpk + ((size_t)fb * 64 + l) * 8) = p;
  }
}

__device__ inline void csr_body(SmU& sm, int b, const Args& a) {
  const int tid = threadIdx.x;
  int bc = (tid < NB) ? min(a.bcnt[tid], BCAP) : 0;
  sm.csr.lh[tid] = bc;
  __syncthreads();
  int val = bc;
#pragma unroll
  for (int off = 1; off < 256; off <<= 1) {
    int t = (tid >= off) ? sm.csr.lh[tid - off] : 0;
    __syncthreads();
    val += t;
    sm.csr.lh[tid] = val;
    __syncthreads();
  }
  if (tid == b) { sm.csr.s_base = val - bc; sm.csr.s_cnt = bc; }
  if (b == 0 && tid == 255) a.offsets[NN] = val;
  __syncthreads();
  const int base = sm.csr.s_base;
  const int cnt = sm.csr.s_cnt;
  const unsigned* ep = a.bedg + (size_t)b * BCAP;
  sm.csr.lh[tid] = 0;
  __syncthreads();
  for (int i = tid; i < cnt; i += 256) atomicAdd(&sm.csr.lh[(ep[i] >> 16) & 255], 1);
  __syncthreads();
  int c0 = sm.csr.lh[tid];
  val = c0;
#pragma unroll
  for (int off = 1; off < 256; off <<= 1) {
    int t = (tid >= off) ? sm.csr.lh[tid - off] : 0;
    __syncthreads();
    val += t;
    sm.csr.lh[tid] = val;
    __syncthreads();
  }
  int excl = val - c0;
  sm.csr.lex[tid] = excl;
  sm.csr.lc[tid] = excl;
  int node = b * 256 + tid;
  if (node < NN) a.offsets[node] = base + excl;
  __syncthreads();
  for (int i = tid; i < cnt; i += 256) {
    unsigned v = ep[i];
    int ld = (v >> 16) & 255;
    int p = atomicAdd(&sm.csr.lc[ld], 1);
    sm.csr.sbuf[p] = (unsigned short)(v & 0xffffu);
  }
  __syncthreads();
  for (int i = tid; i < cnt; i += 256) a.srcs[base + i] = sm.csr.sbuf[i];
  __syncthreads();
}

__device__ inline void in_msg_body(SmU& sm, int ut, const Args& a) {
  _Float16* tile = sm.tile;
  const int tid = threadIdx.x;
  const int w = tid >> 6, l = tid & 63;
  const int m0 = ut * 64;
  const int lr = w * 16 + (l & 15);
  const int kb = (l >> 4) * 8;
  const int row = m0 + lr;
  const _Float16* Wi = a.wpk;
  const _Float16* Wm = a.wpk + (size_t)8 * 512;
  half8 a0 = {}, a1 = {};
  if (row < NN) {
    const float* xp = a.x + (size_t)row * 64 + kb;
    a0 = cvt8(*(const float4*)xp, *(const float4*)(xp + 4));
    a1 = cvt8(*(const float4*)(xp + 32), *(const float4*)(xp + 36));
  }
  f32x4 acc[4] = {};
  const _Float16* wp = Wi + (size_t)l * 8;
#pragma unroll
  for (int nt = 0; nt < 4; ++nt) {
    half8 b0 = *(const half8*)(wp + (size_t)(nt * 2 + 0) * 512);
    half8 b1 = *(const half8*)(wp + (size_t)(nt * 2 + 1) * 512);
    acc[nt] = __builtin_amdgcn_mfma_f32_16x16x32_f16(a0, b0, acc[nt], 0, 0, 0);
    acc[nt] = __builtin_amdgcn_mfma_f32_16x16x32_f16(a1, b1, acc[nt], 0, 0, 0);
  }
  const int crow = w * 16 + (l >> 4) * 4;
#pragma unroll
  for (int nt = 0; nt < 4; ++nt) {
    int col = nt * 16 + (l & 15);
    float bv = a.b_in[col];
#pragma unroll
    for (int g = 0; g < 4; ++g) {
      float v = fmaxf(acc[nt][g] + bv, 0.f);
      size_t idx = (size_t)(m0 + crow + g) * 64 + col;
      a.state_f[idx] = v;
      lds_put(tile, crow + g, col, v);
    }
  }
  __syncthreads();
  half8 n0 = lds_frag(tile, lr, kb);
  half8 n1 = lds_frag(tile, lr, kb + 32);
  f32x4 am[4] = {};
  const _Float16* wm = Wm + (size_t)l * 8;
#pragma unroll
  for (int nt = 0; nt < 4; ++nt) {
    half8 b0 = *(const half8*)(wm + (size_t)(nt * 2 + 0) * 512);
    half8 b1 = *(const half8*)(wm + (size_t)(nt * 2 + 1) * 512);
    am[nt] = __builtin_amdgcn_mfma_f32_16x16x32_f16(n0, b0, am[nt], 0, 0, 0);
    am[nt] = __builtin_amdgcn_mfma_f32_16x16x32_f16(n1, b1, am[nt], 0, 0, 0);
  }
#pragma unroll
  for (int nt = 0; nt < 4; ++nt) {
    int col = nt * 16 + (l & 15);
    float bv = a.msg_b[col];
#pragma unroll
    for (int g = 0; g < 4; ++g) {
      float v = fmaxf(am[nt][g] + bv, 0.f);
      a.msg0[(size_t)(m0 + crow + g) * 64 + col] = (_Float16)v;
    }
  }
  __syncthreads();
}

__device__ inline void agg_body(int h, int c, const _Float16* __restrict__ msg,
                                const int* __restrict__ offsets,
                                const unsigned short* __restrict__ srcs,
                                _Float16* __restrict__ agg) {
  float ax = 0.f, ay = 0.f;
  if (h < NN) {
    int beg = offsets[h], end = offsets[h + 1];
    int j = beg;
    for (; j + 8 <= end; j += 8) {
      unsigned v0 = *(const unsigned*)(msg + (size_t)srcs[j    ] * 64 + c * 2);
      unsigned v1 = *(const unsigned*)(msg + (size_t)srcs[j + 1] * 64 + c * 2);
      unsigned v2 = *(const unsigned*)(msg + (size_t)srcs[j + 2] * 64 + c * 2);
      unsigned v3 = *(const unsigned*)(msg + (size_t)srcs[j + 3] * 64 + c * 2);
      unsigned v4 = *(const unsigned*)(msg + (size_t)srcs[j + 4] * 64 + c * 2);
      unsigned v5 = *(const unsigned*)(msg + (size_t)srcs[j + 5] * 64 + c * 2);
      unsigned v6 = *(const unsigned*)(msg + (size_t)srcs[j + 6] * 64 + c * 2);
      unsigned v7 = *(const unsigned*)(msg + (size_t)srcs[j + 7] * 64 + c * 2);
      ax += h2f(v0 & 0xffffu) + h2f(v1 & 0xffffu) + h2f(v2 & 0xffffu) + h2f(v3 & 0xffffu)
          + h2f(v4 & 0xffffu) + h2f(v5 & 0xffffu) + h2f(v6 & 0xffffu) + h2f(v7 & 0xffffu);
      ay += h2f(v0 >> 16) + h2f(v1 >> 16) + h2f(v2 >> 16) + h2f(v3 >> 16)
          + h2f(v4 >> 16) + h2f(v5 >> 16) + h2f(v6 >> 16) + h2f(v7 >> 16);
    }
    for (; j + 2 <= end; j += 2) {
      unsigned v0 = *(const unsigned*)(msg + (size_t)srcs[j] * 64 + c * 2);
      unsigned v1 = *(const unsigned*)(msg + (size_t)srcs[j + 1] * 64 + c * 2);
      ax += h2f(v0 & 0xffffu) + h2f(v1 & 0xffffu);
      ay += h2f(v0 >> 16) + h2f(v1 >> 16);
    }
    if (j < end) {
      unsigned v0 = *(const unsigned*)(msg + (size_t)srcs[j] * 64 + c * 2);
      ax += h2f(v0 & 0xffffu);
      ay += h2f(v0 >> 16);
    }
  }
  unsigned o = (unsigned)f2h(ax) | ((unsigned)f2h(ay) << 16);
  *(unsigned*)(agg + (size_t)h * 64 + c * 2) = o;
}

__device__ inline void fused_body(SmU& sm, int ut, int r, int last, const Args& a,
                                  _Float16* msg_out) {
  _Float16* tile = sm.tile;
  const int tid = threadIdx.x;
  const int w = tid >> 6, l = tid & 63;
  const int m0 = ut * 64;
  const int lr = w * 16 + (l & 15);
  const int kb = (l >> 4) * 8;
  const _Float16* Wr = a.wpk + (size_t)(32 + r * 16) * 512;
  const _Float16* Wu = a.wpk + (size_t)(80 + r * 16) * 512;
  const _Float16* Wc = a.wpk + (size_t)(128 + r * 16) * 512;
  const float* br = a.rs_b + (size_t)r * 64;
  const float* bu = a.up_b + (size_t)r * 64;
  const float* bc = a.cd_b + (size_t)r * 64;
  const float* sp = a.state_f + (size_t)(m0 + lr) * 64 + kb;
  const _Float16* gp = a.agg + (size_t)(m0 + lr) * 64 + kb;
  float4 u0 = *(const float4*)sp;
  float4 u1 = *(const float4*)(sp + 4);
  float4 u2 = *(const float4*)(sp + 32);
  float4 u3 = *(const float4*)(sp + 36);
  half8 gf0 = *(const half8*)gp;
  half8 gf1 = *(const half8*)(gp + 32);
  half8 sf0 = cvt8(u0, u1);
  half8 sf1 = cvt8(u2, u3);
  f32x4 aR[4] = {}, aU[4] = {};
  {
    const _Float16* wr = Wr + (size_t)l * 8;
    const _Float16* wu = Wu + (size_t)l * 8;
#pragma unroll
    for (int nt = 0; nt < 4; ++nt) {
      aR[nt] = __builtin_amdgcn_mfma_f32_16x16x32_f16(sf0, *(const half8*)(wr + (size_t)(nt * 4 + 0) * 512), aR[nt], 0, 0, 0);
      aR[nt] = __builtin_amdgcn_mfma_f32_16x16x32_f16(sf1, *(const half8*)(wr + (size_t)(nt * 4 + 1) * 512), aR[nt], 0, 0, 0);
      aR[nt] = __builtin_amdgcn_mfma_f32_16x16x32_f16(gf0, *(const half8*)(wr + (size_t)(nt * 4 + 2) * 512), aR[nt], 0, 0, 0);
      aR[nt] = __builtin_amdgcn_mfma_f32_16x16x32_f16(gf1, *(const half8*)(wr + (size_t)(nt * 4 + 3) * 512), aR[nt], 0, 0, 0);
    }
#pragma unroll
    for (int nt = 0; nt < 4; ++nt) {
      aU[nt] = __builtin_amdgcn_mfma_f32_16x16x32_f16(sf0, *(const half8*)(wu + (size_t)(nt * 4 + 0) * 512), aU[nt], 0, 0, 0);
      aU[nt] = __builtin_amdgcn_mfma_f32_16x16x32_f16(sf1, *(const half8*)(wu + (size_t)(nt * 4 + 1) * 512), aU[nt], 0, 0, 0);
      aU[nt] = __builtin_amdgcn_mfma_f32_16x16x32_f16(gf0, *(const half8*)(wu + (size_t)(nt * 4 + 2) * 512), aU[nt], 0, 0, 0);
      aU[nt] = __builtin_amdgcn_mfma_f32_16x16x32_f16(gf1, *(const half8*)(wu + (size_t)(nt * 4 + 3) * 512), aU[nt], 0, 0, 0);
    }
  }
  const int crow = w * 16 + (l >> 4) * 4;
#pragma unroll
  for (int nt = 0; nt < 4; ++nt) {
    int col = nt * 16 + (l & 15);
    float brv = br[col], buv = bu[col];
#pragma unroll
    for (int g = 0; g < 4; ++g) {
      lds_put(tile, crow + g, col, sigm(aR[nt][g] + brv));
      aU[nt][g] = sigm(aU[nt][g] + buv);
    }
  }
  __syncthreads();
  half8 rf0 = lds_frag(tile, lr, kb);
  half8 rf1 = lds_frag(tile, lr, kb + 32);
  __syncthreads();
  half8 a0, a1;
#pragma unroll
  for (int i = 0; i < 8; ++i) {
    a0[i] = (_Float16)((float)sf0[i] * (float)rf0[i]);
    a1[i] = (_Float16)((float)sf1[i] * (float)rf1[i]);
  }
  f32x4 aC[4] = {};
  {
    const _Float16* wc = Wc + (size_t)l * 8;
#pragma unroll
    for (int nt = 0; nt < 4; ++nt) {
      aC[nt] = __builtin_amdgcn_mfma_f32_16x16x32_f16(a0, *(const half8*)(wc + (size_t)(nt * 4 + 0) * 512), aC[nt], 0, 0, 0);
      aC[nt] = __builtin_amdgcn_mfma_f32_16x16x32_f16(a1, *(const half8*)(wc + (size_t)(nt * 4 + 1) * 512), aC[nt], 0, 0, 0);
      aC[nt] = __builtin_amdgcn_mfma_f32_16x16x32_f16(gf0, *(const half8*)(wc + (size_t)(nt * 4 + 2) * 512), aC[nt], 0, 0, 0);
      aC[nt] = __builtin_amdgcn_mfma_f32_16x16x32_f16(gf1, *(const half8*)(wc + (size_t)(nt * 4 + 3) * 512), aC[nt], 0, 0, 0);
    }
  }
#pragma unroll
  for (int nt = 0; nt < 4; ++nt) {
    int col = nt * 16 + (l & 15);
    float bcv = bc[col];
#pragma unroll
    for (int g = 0; g < 4; ++g) {
      int rr = m0 + crow + g;
      size_t idx = (size_t)rr * 64 + col;
      float th = tanh_f(aC[nt][g] + bcv);
      float u = aU[nt][g];
      float s = a.state_f[idx];
      float o = s + u * (th - s);
      if (last) {
        if (rr < NN) a.out[idx] = o;
      } else {
        a.state_f[idx] = o;
        lds_put(tile, crow + g, col, o);
      }
    }
  }
  if (!last) {
    __syncthreads();
    half8 n0 = lds_frag(tile, lr, kb);
    half8 n1 = lds_frag(tile, lr, kb + 32);
    f32x4 am[4] = {};
    const _Float16* wm = a.wpk + (size_t)(8 + (r + 1) * 8) * 512 + (size_t)l * 8;
    const float* bm = a.msg_b + (size_t)(r + 1) * 64;
#pragma unroll
    for (int nt = 0; nt < 4; ++nt) {
      am[nt] = __builtin_amdgcn_mfma_f32_16x16x32_f16(n0, *(const half8*)(wm + (size_t)(nt * 2 + 0) * 512), am[nt], 0, 0, 0);
      am[nt] = __builtin_amdgcn_mfma_f32_16x16x32_f16(n1, *(const half8*)(wm + (size_t)(nt * 2 + 1) * 512), am[nt], 0, 0, 0);
    }
#pragma unroll
    for (int nt = 0; nt < 4; ++nt) {
      int col = nt * 16 + (l & 15);
      float bv = bm[col];
#pragma unroll
      for (int g = 0; g < 4; ++g) {
        float v = fmaxf(am[nt][g] + bv, 0.f);
        msg_out[(size_t)(m0 + crow + g) * 64 + col] = (_Float16)v;
      }
    }
  }
  __syncthreads();
}

// ===================== the mega cooperative kernel =====================
__global__ __launch_bounds__(256, 4) void mega(Args a) {
  cg::grid_group grid = cg::this_grid();
  __shared__ SmU sm;
  const int nblk = gridDim.x;
  const int tid = threadIdx.x;

  // phase 1: bin (0..195) || pack (196..239)
  for (int u = blockIdx.x; u < NB + 44; u += nblk) {
    if (u < NB) bin_body(sm, u, a);
    else pack_body(u - NB, a);
  }
  __threadfence();
  grid.sync();
  __threadfence();

  // phase 2: csr (0..195) || in_msg (196..977)
  for (int u = blockIdx.x; u < NB + NT; u += nblk) {
    if (u < NB) csr_body(sm, u, a);
    else in_msg_body(sm, u - NB, a);
  }
  __threadfence();
  grid.sync();
  __threadfence();

  // rounds
  const int nhw = nblk * 8;
  const int hw0 = blockIdx.x * 8 + (tid >> 5);
  const int c = tid & 31;
  for (int r = 0; r < 3; ++r) {
    const _Float16* min_ = (r & 1) ? a.msg1 : a.msg0;
    _Float16* mout = (r & 1) ? a.msg0 : a.msg1;
    for (int h = hw0; h < MP; h += nhw)
      agg_body(h, c, min_, a.offsets, a.srcs, a.agg);
    __threadfence();
    grid.sync();
    __threadfence();
    for (int u = blockIdx.x; u < NT; u += nblk)
      fused_body(sm, u, r, r == 2, a, mout);
    __threadfence();
    grid.sync();
    __threadfence();
  }
}

// ===================== fallback kernels (old 8-dispatch path) =====================
__global__ __launch_bounds__(256) void prep_a_k(const int* src, const int* dst, int* bcnt, unsigned* bedg,
                                                const float* W_in, const float* msg_W, const float* rs_W,
                                                const float* up_W, const float* cd_W, _Float16* wpk) {
  __shared__ SmU sm;
  Args a = {}; a.src = src; a.dst = dst; a.bcnt = bcnt; a.bedg = bedg;
  a.W_in = W_in; a.msg_W = msg_W; a.rs_W = rs_W; a.up_W = up_W; a.cd_W = cd_W; a.wpk = wpk;
  if (blockIdx.x < NB) bin_body(sm, blockIdx.x, a);
  else pack_body(blockIdx.x - NB, a);
}

__global__ __launch_bounds__(256) void prep_b_k(const unsigned* bedg, const int* bcnt,
                                                unsigned short* srcs, int* offsets, const float* x,
                                                const _Float16* wpk, const float* bi, const float* bm,
                                                float* S_f, _Float16* msg0) {
  __shared__ SmU sm;
  Args a = {}; a.bedg = (unsigned*)bedg; a.bcnt = (int*)bcnt; a.srcs = srcs; a.offsets = offsets;
  a.x = x; a.wpk = (_Float16*)wpk; a.b_in = bi; a.msg_b = bm; a.state_f = S_f; a.msg0 = msg0;
  if (blockIdx.x < NB) csr_body(sm, blockIdx.x, a);
  else in_msg_body(sm, blockIdx.x - NB, a);
}

__global__ __launch_bounds__(256) void aggregate_k(const _Float16* msg, const int* offsets,
                                                   const unsigned short* srcs, _Float16* agg) {
  int h = (blockIdx.x * 256 + threadIdx.x) >> 5;
  int c = threadIdx.x & 31;
  if (h >= MP) return;
  agg_body(h, c, msg, offsets, srcs, agg);
}

template<int LAST>
__global__ __launch_bounds__(256) void fused_k(Args a, int r, _Float16* mout) {
  __shared__ SmU sm;
  fused_body(sm, blockIdx.x, r, LAST, a, mout);
}

// ======================= launch =======================
extern "C" void kernel_launch(void* const* d_in, const int* in_sizes, int n_in,
                              void* d_out, int out_size, void* d_ws, size_t ws_size,
                              hipStream_t stream) {
  const float* x     = (const float*)d_in[0];
  const int*   ei    = (const int*)d_in[1];
  const float* W_in  = (const float*)d_in[3];
  const float* b_in  = (const float*)d_in[4];
  const float* msg_W = (const float*)d_in[5];
  const float* msg_b = (const float*)d_in[6];
  const float* rs_W  = (const float*)d_in[7];
  const float* rs_b  = (const float*)d_in[8];
  const float* up_W  = (const float*)d_in[9];
  const float* up_b  = (const float*)d_in[10];
  const float* cd_W  = (const float*)d_in[11];
  const float* cd_b  = (const float*)d_in[12];
  float* out = (float*)d_out;

  const int* src = ei;
  const int* dst = ei + NE;

  char* ws = (char*)d_ws;
  size_t off = 0;
  auto alloc = [&](size_t bytes) -> void* {
    void* p = (void*)(ws + off);
    off += (bytes + 255) & ~((size_t)255);
    return p;
  };
  float*     state_f = (float*)alloc((size_t)MP * 64 * 4);
  _Float16*  msg0    = (_Float16*)alloc((size_t)MP * 64 * 2);
  _Float16*  msg1    = (_Float16*)alloc((size_t)MP * 64 * 2);
  _Float16*  agg_h   = (_Float16*)alloc((size_t)MP * 64 * 2);
  _Float16*  wpk     = (_Float16*)alloc((size_t)176 * 512 * 2);
  int*       bcnt    = (int*)alloc((size_t)NB * 4);
  unsigned*  bedg    = (unsigned*)alloc((size_t)NB * BCAP * 4);
  unsigned short* srcs = (unsigned short*)alloc((size_t)NE * 2);
  int*       offsets = (int*)alloc((size_t)(NN + 1) * 4);
  (void)ws_size; (void)in_sizes; (void)n_in; (void)out_size;

  hipMemsetAsync(bcnt, 0, (size_t)NB * 4, stream);

  Args a;
  a.src = src; a.dst = dst; a.bcnt = bcnt; a.bedg = bedg;
  a.W_in = W_in; a.msg_W = msg_W; a.rs_W = rs_W; a.up_W = up_W; a.cd_W = cd_W;
  a.wpk = wpk; a.srcs = srcs; a.offsets = offsets; a.x = x;
  a.b_in = b_in; a.msg_b = msg_b; a.rs_b = rs_b; a.up_b = up_b; a.cd_b = cd_b;
  a.state_f = state_f; a.msg0 = msg0; a.msg1 = msg1; a.agg = agg_h; a.out = out;

  int occ = 0;
  hipError_t oe = hipOccupancyMaxActiveBlocksPerMultiprocessor(&occ, (const void*)mega, 256, 0);
  bool coop_ok = (oe == hipSuccess && occ >= 1);
  if (coop_ok) {
    int grid = occ * 256;
    if (grid > 1024) grid = 1024;
    void* kargs[] = { (void*)&a };
    hipError_t st = hipLaunchCooperativeKernel((const void*)mega, dim3(grid), dim3(256), kargs, 0, stream);
    coop_ok = (st == hipSuccess);
  }
  if (!coop_ok) {
    // fallback: classic 8-dispatch path
    prep_a_k<<<NB + 44, 256, 0, stream>>>(src, dst, bcnt, bedg, W_in, msg_W, rs_W, up_W, cd_W, wpk);
    prep_b_k<<<NB + NT, 256, 0, stream>>>(bedg, bcnt, srcs, offsets, x, wpk, b_in, msg_b, state_f, msg0);
    for (int r = 0; r < 3; ++r) {
      _Float16* min_ = (r & 1) ? msg1 : msg0;
      _Float16* mout = (r & 1) ? msg0 : msg1;
      aggregate_k<<<(MP * 32 + 255) / 256, 256, 0, stream>>>(min_, offsets, srcs, agg_h);
      if (r < 2) fused_k<0><<<NT, 256, 0, stream>>>(a, r, mout);
      else       fused_k<1><<<NT, 256, 0, stream>>>(a, r, nullptr);
    }
  }
}

// Round 10
// 147.141 us; speedup vs baseline: 10.1121x; 10.1121x over previous
//
#include <hip/hip_runtime.h>
#include <cstdint>
#include <cstddef>

#define NN 50000
#define MP 50048   // rows padded to multiple of 64
#define NE 800000
#define NB 196     // buckets of 256 nodes (dst >> 8)
#define BCAP 5120  // per-bucket edge capacity (mean 4082, sigma ~64)
#define EPB 4096   // edges per bin_edges block

typedef __attribute__((ext_vector_type(8))) _Float16 half8;
typedef __attribute__((ext_vector_type(4))) float f32x4;

__device__ inline unsigned short f2h(float f){
  _Float16 h = (_Float16)f;
  return *(unsigned short*)&h;
}
__device__ inline float h2f(unsigned u){
  _Float16 h = *(_Float16*)&u;
  return (float)h;
}
__device__ inline float fast_rcp(float x){ return __builtin_amdgcn_rcpf(x); }
__device__ inline float sigm(float z){ return fast_rcp(1.f + __expf(-z)); }
__device__ inline float tanh_f(float z){
  z = fminf(fmaxf(z, -15.f), 15.f);
  float e = __expf(2.f * z);
  return 1.f - 2.f * fast_rcp(e + 1.f);
}

// LDS 64x64 fp16 tile, XOR-swizzled in 16B chunks: chunk ^= (row&7)
__device__ inline half8 lds_frag(const _Float16* tile, int row, int kb){
  return *(const half8*)(tile + row * 64 + ((((kb) >> 3) ^ (row & 7)) << 3));
}
__device__ inline void lds_put(_Float16* tile, int row, int col, float v){
  tile[row * 64 + ((((col) >> 3) ^ (row & 7)) << 3) + (col & 7)] = (_Float16)v;
}
// convert 8 fp32 (two float4) -> half8
__device__ inline half8 cvt8(float4 a, float4 b){
  half8 h;
  h[0] = (_Float16)a.x; h[1] = (_Float16)a.y; h[2] = (_Float16)a.z; h[3] = (_Float16)a.w;
  h[4] = (_Float16)b.x; h[5] = (_Float16)b.y; h[6] = (_Float16)b.z; h[7] = (_Float16)b.w;
  return h;
}

// ======================= kernel A: bin_edges (blocks 0..195) || pack_w (blocks 196..239) ==========
__global__ __launch_bounds__(256) void prep_a(const int* __restrict__ src, const int* __restrict__ dst,
                                              int* __restrict__ bcnt, unsigned* __restrict__ bedg,
                                              const float* __restrict__ W_in, const float* __restrict__ msg_W,
                                              const float* __restrict__ rs_W, const float* __restrict__ up_W,
                                              const float* __restrict__ cd_W, _Float16* __restrict__ wpk) {
  __shared__ unsigned buf[EPB];
  __shared__ unsigned char sb[EPB];
  __shared__ int lh[256];
  __shared__ int lex[256];
  __shared__ int lc[256];
  __shared__ int gb[256];
  const int tid = threadIdx.x;
  if (blockIdx.x >= NB) {
    // ---- pack_w: 4 frag-rows per block ----
    int fb = (blockIdx.x - NB) * 4 + (tid >> 6);
    int l = tid & 63;
    if (fb < 176) {
      const float* W; int KT, fi;
      if (fb < 8)        { W = W_in;                            KT = 2; fi = fb; }
      else if (fb < 32)  { int r = (fb - 8) >> 3;   W = msg_W + (size_t)r * 64 * 64;  KT = 2; fi = (fb - 8) & 7; }
      else if (fb < 80)  { int r = (fb - 32) >> 4;  W = rs_W + (size_t)r * 128 * 64;  KT = 4; fi = (fb - 32) & 15; }
      else if (fb < 128) { int r = (fb - 80) >> 4;  W = up_W + (size_t)r * 128 * 64;  KT = 4; fi = (fb - 80) & 15; }
      else               { int r = (fb - 128) >> 4; W = cd_W + (size_t)r * 128 * 64;  KT = 4; fi = (fb - 128) & 15; }
      int nt = fi / KT, kt = fi % KT;
      int rb = kt * 32 + (l >> 4) * 8;
      int col = nt * 16 + (l & 15);
      half8 p;
#pragma unroll
      for (int i = 0; i < 8; ++i) p[i] = (_Float16)W[(size_t)(rb + i) * 64 + col];
      *(half8*)(wpk + ((size_t)fb * 64 + l) * 8) = p;
    }
    return;
  }
  // ---- bin_edges ----
  const int e0 = blockIdx.x * EPB;
  const int tot = min(EPB, NE - e0);
  lh[tid] = 0;
  __syncthreads();
  for (int i = tid; i < tot; i += 256) {
    int b = dst[e0 + i] >> 8;
    atomicAdd(&lh[b], 1);
  }
  __syncthreads();
  int cnt = lh[tid];
  int val = cnt;
#pragma unroll
  for (int off = 1; off < 256; off <<= 1) {
    int t = (tid >= off) ? lh[tid - off] : 0;
    __syncthreads();
    val += t;
    lh[tid] = val;
    __syncthreads();
  }
  int excl = val - cnt;
  lex[tid] = excl;
  lc[tid] = excl;
  if (tid < NB && cnt > 0) gb[tid] = atomicAdd(&bcnt[tid], cnt);
  else gb[tid] = 0;
  __syncthreads();
  for (int i = tid; i < tot; i += 256) {
    int s = src[e0 + i], d = dst[e0 + i];
    int b = d >> 8;
    int p = atomicAdd(&lc[b], 1);
    buf[p] = (unsigned)s | ((unsigned)(d & 255) << 16);
    sb[p] = (unsigned char)b;
  }
  __syncthreads();
  for (int i = tid; i < tot; i += 256) {
    int b = sb[i];
    int gpos = gb[b] + (i - lex[b]);
    if (gpos < BCAP) bedg[(size_t)b * BCAP + gpos] = buf[i];
  }
}

// ======================= kernel B: build_csr2 (blocks 0..195) || in_msg (blocks 196..977) =========
union SmemB {
  struct {
    unsigned short sbuf[BCAP];
    int lh[256]; int lex[256]; int lc[256];
    int s_base, s_cnt;
  } csr;
  _Float16 tile[64 * 64];
};

__global__ __launch_bounds__(256) void prep_b(const unsigned* __restrict__ bedg, const int* __restrict__ bcnt,
                                              unsigned short* __restrict__ srcs, int* __restrict__ offsets,
                                              const float* __restrict__ x,
                                              const _Float16* __restrict__ wpk,
                                              const float* __restrict__ bi, const float* __restrict__ bm,
                                              float* __restrict__ S_f,
                                              _Float16* __restrict__ msg0) {
  __shared__ SmemB sm;
  const int tid = threadIdx.x;
  if (blockIdx.x < NB) {
    // ---- build_csr2 ----
    const int b = blockIdx.x;
    int bc = (tid < NB) ? min(bcnt[tid], BCAP) : 0;
    sm.csr.lh[tid] = bc;
    __syncthreads();
    int val = bc;
#pragma unroll
    for (int off = 1; off < 256; off <<= 1) {
      int t = (tid >= off) ? sm.csr.lh[tid - off] : 0;
      __syncthreads();
      val += t;
      sm.csr.lh[tid] = val;
      __syncthreads();
    }
    if (tid == b) { sm.csr.s_base = val - bc; sm.csr.s_cnt = bc; }
    if (b == 0 && tid == 255) offsets[NN] = val;
    __syncthreads();
    const int base = sm.csr.s_base;
    const int cnt = sm.csr.s_cnt;
    const unsigned* ep = bedg + (size_t)b * BCAP;
    sm.csr.lh[tid] = 0;
    __syncthreads();
    for (int i = tid; i < cnt; i += 256) atomicAdd(&sm.csr.lh[(ep[i] >> 16) & 255], 1);
    __syncthreads();
    int c0 = sm.csr.lh[tid];
    val = c0;
#pragma unroll
    for (int off = 1; off < 256; off <<= 1) {
      int t = (tid >= off) ? sm.csr.lh[tid - off] : 0;
      __syncthreads();
      val += t;
      sm.csr.lh[tid] = val;
      __syncthreads();
    }
    int excl = val - c0;
    sm.csr.lex[tid] = excl;
    sm.csr.lc[tid] = excl;
    int node = b * 256 + tid;
    if (node < NN) offsets[node] = base + excl;
    __syncthreads();
    for (int i = tid; i < cnt; i += 256) {
      unsigned v = ep[i];
      int ld = (v >> 16) & 255;
      int p = atomicAdd(&sm.csr.lc[ld], 1);
      sm.csr.sbuf[p] = (unsigned short)(v & 0xffffu);
    }
    __syncthreads();
    for (int i = tid; i < cnt; i += 256) srcs[base + i] = sm.csr.sbuf[i];
    return;
  }
  // ---- in_msg: input GEMM + msg[0] GEMM ----
  _Float16* tile = sm.tile;
  const int w = tid >> 6, l = tid & 63;
  const int m0 = (blockIdx.x - NB) * 64;
  const int lr = w * 16 + (l & 15);
  const int kb = (l >> 4) * 8;
  const int row = m0 + lr;
  const _Float16* Wi = wpk;
  const _Float16* Wm = wpk + (size_t)8 * 512;
  half8 a0 = {}, a1 = {};
  if (row < NN) {
    const float* xp = x + (size_t)row * 64 + kb;
    a0 = cvt8(*(const float4*)xp, *(const float4*)(xp + 4));
    a1 = cvt8(*(const float4*)(xp + 32), *(const float4*)(xp + 36));
  }
  f32x4 acc[4] = {};
  const _Float16* wp = Wi + (size_t)l * 8;
#pragma unroll
  for (int nt = 0; nt < 4; ++nt) {
    half8 b0 = *(const half8*)(wp + (size_t)(nt * 2 + 0) * 512);
    half8 b1 = *(const half8*)(wp + (size_t)(nt * 2 + 1) * 512);
    acc[nt] = __builtin_amdgcn_mfma_f32_16x16x32_f16(a0, b0, acc[nt], 0, 0, 0);
    acc[nt] = __builtin_amdgcn_mfma_f32_16x16x32_f16(a1, b1, acc[nt], 0, 0, 0);
  }
  const int crow = w * 16 + (l >> 4) * 4;
#pragma unroll
  for (int nt = 0; nt < 4; ++nt) {
    int col = nt * 16 + (l & 15);
    float bv = bi[col];
#pragma unroll
    for (int g = 0; g < 4; ++g) {
      float v = fmaxf(acc[nt][g] + bv, 0.f);
      size_t idx = (size_t)(m0 + crow + g) * 64 + col;
      S_f[idx] = v;
      lds_put(tile, crow + g, col, v);
    }
  }
  __syncthreads();
  half8 n0 = lds_frag(tile, lr, kb);
  half8 n1 = lds_frag(tile, lr, kb + 32);
  f32x4 am[4] = {};
  const _Float16* wm = Wm + (size_t)l * 8;
#pragma unroll
  for (int nt = 0; nt < 4; ++nt) {
    half8 b0 = *(const half8*)(wm + (size_t)(nt * 2 + 0) * 512);
    half8 b1 = *(const half8*)(wm + (size_t)(nt * 2 + 1) * 512);
    am[nt] = __builtin_amdgcn_mfma_f32_16x16x32_f16(n0, b0, am[nt], 0, 0, 0);
    am[nt] = __builtin_amdgcn_mfma_f32_16x16x32_f16(n1, b1, am[nt], 0, 0, 0);
  }
#pragma unroll
  for (int nt = 0; nt < 4; ++nt) {
    int col = nt * 16 + (l & 15);
    float bv = bm[col];
#pragma unroll
    for (int g = 0; g < 4; ++g) {
      float v = fmaxf(am[nt][g] + bv, 0.f);
      msg0[(size_t)(m0 + crow + g) * 64 + col] = (_Float16)v;
    }
  }
}

// ======================= aggregation: standalone gather, half-wave per node, 8-deep ILP ============
__global__ __launch_bounds__(256) void aggregate_h(const _Float16* __restrict__ msg,
                                                   const int* __restrict__ offsets,
                                                   const unsigned short* __restrict__ srcs,
                                                   _Float16* __restrict__ agg) {
  int h = (blockIdx.x * 256 + threadIdx.x) >> 5;   // half-wave = node
  int c = threadIdx.x & 31;
  if (h >= MP) return;
  float ax = 0.f, ay = 0.f;
  if (h < NN) {
    int beg = offsets[h], end = offsets[h + 1];
    int j = beg;
    for (; j + 8 <= end; j += 8) {
      unsigned v0 = *(const unsigned*)(msg + (size_t)srcs[j    ] * 64 + c * 2);
      unsigned v1 = *(const unsigned*)(msg + (size_t)srcs[j + 1] * 64 + c * 2);
      unsigned v2 = *(const unsigned*)(msg + (size_t)srcs[j + 2] * 64 + c * 2);
      unsigned v3 = *(const unsigned*)(msg + (size_t)srcs[j + 3] * 64 + c * 2);
      unsigned v4 = *(const unsigned*)(msg + (size_t)srcs[j + 4] * 64 + c * 2);
      unsigned v5 = *(const unsigned*)(msg + (size_t)srcs[j + 5] * 64 + c * 2);
      unsigned v6 = *(const unsigned*)(msg + (size_t)srcs[j + 6] * 64 + c * 2);
      unsigned v7 = *(const unsigned*)(msg + (size_t)srcs[j + 7] * 64 + c * 2);
      ax += h2f(v0 & 0xffffu) + h2f(v1 & 0xffffu) + h2f(v2 & 0xffffu) + h2f(v3 & 0xffffu)
          + h2f(v4 & 0xffffu) + h2f(v5 & 0xffffu) + h2f(v6 & 0xffffu) + h2f(v7 & 0xffffu);
      ay += h2f(v0 >> 16) + h2f(v1 >> 16) + h2f(v2 >> 16) + h2f(v3 >> 16)
          + h2f(v4 >> 16) + h2f(v5 >> 16) + h2f(v6 >> 16) + h2f(v7 >> 16);
    }
    for (; j + 2 <= end; j += 2) {
      unsigned v0 = *(const unsigned*)(msg + (size_t)srcs[j] * 64 + c * 2);
      unsigned v1 = *(const unsigned*)(msg + (size_t)srcs[j + 1] * 64 + c * 2);
      ax += h2f(v0 & 0xffffu) + h2f(v1 & 0xffffu);
      ay += h2f(v0 >> 16) + h2f(v1 >> 16);
    }
    if (j < end) {
      unsigned v0 = *(const unsigned*)(msg + (size_t)srcs[j] * 64 + c * 2);
      ax += h2f(v0 & 0xffffu);
      ay += h2f(v0 >> 16);
    }
  }
  unsigned o = (unsigned)f2h(ax) | ((unsigned)f2h(ay) << 16);
  *(unsigned*)(agg + (size_t)h * 64 + c * 2) = o;
}

// ======================= fused: RU GEMM + CD GEMM + GRU epilogue (+ next msg GEMM) =======================
// state kept fp32-only; MFMA fragments converted in-kernel.
template<int LAST>
__global__ __launch_bounds__(256) void fused_rcm(
    const float* __restrict__ S_f,
    const _Float16* __restrict__ G,
    const _Float16* __restrict__ Wr, const _Float16* __restrict__ Wu, const _Float16* __restrict__ Wc,
    const _Float16* __restrict__ Wm,
    const float* __restrict__ br, const float* __restrict__ bu, const float* __restrict__ bc,
    const float* __restrict__ bm,
    float* __restrict__ O_f, _Float16* __restrict__ msg_out) {
  __shared__ _Float16 tile[64 * 64];    // fp16 swizzled tile for R transpose / state handoff
  const int tid = threadIdx.x, w = tid >> 6, l = tid & 63;
  const int m0 = blockIdx.x * 64;
  const int lr = w * 16 + (l & 15);
  const int kb = (l >> 4) * 8;
  const float* sp = S_f + (size_t)(m0 + lr) * 64 + kb;
  const _Float16* gp = G + (size_t)(m0 + lr) * 64 + kb;
  float4 u0 = *(const float4*)sp;
  float4 u1 = *(const float4*)(sp + 4);
  float4 u2 = *(const float4*)(sp + 32);
  float4 u3 = *(const float4*)(sp + 36);
  half8 gf0 = *(const half8*)gp;
  half8 gf1 = *(const half8*)(gp + 32);
  half8 sf0 = cvt8(u0, u1);
  half8 sf1 = cvt8(u2, u3);
  // ---- RU GEMM: K=128 over [S|G] ----
  f32x4 aR[4] = {}, aU[4] = {};
  {
    const _Float16* wr = Wr + (size_t)l * 8;
    const _Float16* wu = Wu + (size_t)l * 8;
#pragma unroll
    for (int nt = 0; nt < 4; ++nt) {
      aR[nt] = __builtin_amdgcn_mfma_f32_16x16x32_f16(sf0, *(const half8*)(wr + (size_t)(nt * 4 + 0) * 512), aR[nt], 0, 0, 0);
      aR[nt] = __builtin_amdgcn_mfma_f32_16x16x32_f16(sf1, *(const half8*)(wr + (size_t)(nt * 4 + 1) * 512), aR[nt], 0, 0, 0);
      aR[nt] = __builtin_amdgcn_mfma_f32_16x16x32_f16(gf0, *(const half8*)(wr + (size_t)(nt * 4 + 2) * 512), aR[nt], 0, 0, 0);
      aR[nt] = __builtin_amdgcn_mfma_f32_16x16x32_f16(gf1, *(const half8*)(wr + (size_t)(nt * 4 + 3) * 512), aR[nt], 0, 0, 0);
    }
#pragma unroll
    for (int nt = 0; nt < 4; ++nt) {
      aU[nt] = __builtin_amdgcn_mfma_f32_16x16x32_f16(sf0, *(const half8*)(wu + (size_t)(nt * 4 + 0) * 512), aU[nt], 0, 0, 0);
      aU[nt] = __builtin_amdgcn_mfma_f32_16x16x32_f16(sf1, *(const half8*)(wu + (size_t)(nt * 4 + 1) * 512), aU[nt], 0, 0, 0);
      aU[nt] = __builtin_amdgcn_mfma_f32_16x16x32_f16(gf0, *(const half8*)(wu + (size_t)(nt * 4 + 2) * 512), aU[nt], 0, 0, 0);
      aU[nt] = __builtin_amdgcn_mfma_f32_16x16x32_f16(gf1, *(const half8*)(wu + (size_t)(nt * 4 + 3) * 512), aU[nt], 0, 0, 0);
    }
  }
  const int crow = w * 16 + (l >> 4) * 4;
#pragma unroll
  for (int nt = 0; nt < 4; ++nt) {
    int col = nt * 16 + (l & 15);
    float brv = br[col], buv = bu[col];
#pragma unroll
    for (int g = 0; g < 4; ++g) {
      lds_put(tile, crow + g, col, sigm(aR[nt][g] + brv));
      aU[nt][g] = sigm(aU[nt][g] + buv);   // U stays in registers
    }
  }
  __syncthreads();
  half8 rf0 = lds_frag(tile, lr, kb);
  half8 rf1 = lds_frag(tile, lr, kb + 32);
  __syncthreads();   // all R reads done; tile reusable for new state
  half8 a0, a1;
#pragma unroll
  for (int i = 0; i < 8; ++i) {
    a0[i] = (_Float16)((float)sf0[i] * (float)rf0[i]);
    a1[i] = (_Float16)((float)sf1[i] * (float)rf1[i]);
  }
  // ---- CD GEMM: K=128 over [S*R|G] ----
  f32x4 aC[4] = {};
  {
    const _Float16* wc = Wc + (size_t)l * 8;
#pragma unroll
    for (int nt = 0; nt < 4; ++nt) {
      aC[nt] = __builtin_amdgcn_mfma_f32_16x16x32_f16(a0, *(const half8*)(wc + (size_t)(nt * 4 + 0) * 512), aC[nt], 0, 0, 0);
      aC[nt] = __builtin_amdgcn_mfma_f32_16x16x32_f16(a1, *(const half8*)(wc + (size_t)(nt * 4 + 1) * 512), aC[nt], 0, 0, 0);
      aC[nt] = __builtin_amdgcn_mfma_f32_16x16x32_f16(gf0, *(const half8*)(wc + (size_t)(nt * 4 + 2) * 512), aC[nt], 0, 0, 0);
      aC[nt] = __builtin_amdgcn_mfma_f32_16x16x32_f16(gf1, *(const half8*)(wc + (size_t)(nt * 4 + 3) * 512), aC[nt], 0, 0, 0);
    }
  }
  // ---- GRU epilogue ----
#pragma unroll
  for (int nt = 0; nt < 4; ++nt) {
    int col = nt * 16 + (l & 15);
    float bcv = bc[col];
#pragma unroll
    for (int g = 0; g < 4; ++g) {
      int rr = m0 + crow + g;
      size_t idx = (size_t)rr * 64 + col;
      float th = tanh_f(aC[nt][g] + bcv);
      float u = aU[nt][g];
      float s = S_f[idx];
      float o = s + u * (th - s);
      if (LAST) {
        if (rr < NN) O_f[idx] = o;
      } else {
        O_f[idx] = o;
        lds_put(tile, crow + g, col, o);
      }
    }
  }
  // ---- fused next-round msg GEMM ----
  if (!LAST) {
    __syncthreads();
    half8 n0 = lds_frag(tile, lr, kb);
    half8 n1 = lds_frag(tile, lr, kb + 32);
    f32x4 am[4] = {};
    const _Float16* wm = Wm + (size_t)l * 8;
#pragma unroll
    for (int nt = 0; nt < 4; ++nt) {
      am[nt] = __builtin_amdgcn_mfma_f32_16x16x32_f16(n0, *(const half8*)(wm + (size_t)(nt * 2 + 0) * 512), am[nt], 0, 0, 0);
      am[nt] = __builtin_amdgcn_mfma_f32_16x16x32_f16(n1, *(const half8*)(wm + (size_t)(nt * 2 + 1) * 512), am[nt], 0, 0, 0);
    }
#pragma unroll
    for (int nt = 0; nt < 4; ++nt) {
      int col = nt * 16 + (l & 15);
      float bv = bm[col];
#pragma unroll
      for (int g = 0; g < 4; ++g) {
        float v = fmaxf(am[nt][g] + bv, 0.f);
        msg_out[(size_t)(m0 + crow + g) * 64 + col] = (_Float16)v;
      }
    }
  }
}

// ======================= launch =======================
extern "C" void kernel_launch(void* const* d_in, const int* in_sizes, int n_in,
                              void* d_out, int out_size, void* d_ws, size_t ws_size,
                              hipStream_t stream) {
  const float* x     = (const float*)d_in[0];
  const int*   ei    = (const int*)d_in[1];
  const float* W_in  = (const float*)d_in[3];
  const float* b_in  = (const float*)d_in[4];
  const float* msg_W = (const float*)d_in[5];
  const float* msg_b = (const float*)d_in[6];
  const float* rs_W  = (const float*)d_in[7];
  const float* rs_b  = (const float*)d_in[8];
  const float* up_W  = (const float*)d_in[9];
  const float* up_b  = (const float*)d_in[10];
  const float* cd_W  = (const float*)d_in[11];
  const float* cd_b  = (const float*)d_in[12];
  float* out = (float*)d_out;

  const int* src = ei;
  const int* dst = ei + NE;

  char* ws = (char*)d_ws;
  size_t off = 0;
  auto alloc = [&](size_t bytes) -> void* {
    void* p = (void*)(ws + off);
    off += (bytes + 255) & ~((size_t)255);
    return p;
  };
  float*     state_f = (float*)alloc((size_t)MP * 64 * 4);
  _Float16*  msg0    = (_Float16*)alloc((size_t)MP * 64 * 2);
  _Float16*  msg1    = (_Float16*)alloc((size_t)MP * 64 * 2);
  _Float16*  agg_h   = (_Float16*)alloc((size_t)MP * 64 * 2);
  _Float16*  wpk     = (_Float16*)alloc((size_t)176 * 512 * 2);
  int*       bcnt    = (int*)alloc((size_t)NB * 4);
  unsigned*  bedg    = (unsigned*)alloc((size_t)NB * BCAP * 4);
  unsigned short* srcs = (unsigned short*)alloc((size_t)NE * 2);
  int*       offsets = (int*)alloc((size_t)(NN + 1) * 4);
  (void)ws_size; (void)in_sizes; (void)n_in; (void)out_size;

  auto msg_p = [&](int r){ return wpk + (size_t)(8 + r * 8) * 512; };
  auto rs_p  = [&](int r){ return wpk + (size_t)(32 + r * 16) * 512; };
  auto up_p  = [&](int r){ return wpk + (size_t)(80 + r * 16) * 512; };
  auto cd_p  = [&](int r){ return wpk + (size_t)(128 + r * 16) * 512; };

  hipMemsetAsync(bcnt, 0, (size_t)NB * 4, stream);
  // A: bin_edges (196 blocks) || pack_w (44 blocks)
  prep_a<<<NB + 44, 256, 0, stream>>>(src, dst, bcnt, bedg, W_in, msg_W, rs_W, up_W, cd_W, wpk);
  // B: build_csr2 (196 blocks) || in_msg (782 blocks)
  prep_b<<<NB + MP / 64, 256, 0, stream>>>(bedg, bcnt, srcs, offsets, x, wpk, b_in, msg_b,
                                           state_f, msg0);

  const int GB = MP / 64;  // 782 blocks
  _Float16* mbuf[2] = { msg0, msg1 };
  for (int r = 0; r < 3; ++r) {
    _Float16* min_ = mbuf[r & 1];
    _Float16* mout = mbuf[(r + 1) & 1];
    aggregate_h<<<(MP * 32 + 255) / 256, 256, 0, stream>>>(min_, offsets, srcs, agg_h);
    if (r < 2)
      fused_rcm<0><<<GB, 256, 0, stream>>>(state_f, agg_h,
                                           rs_p(r), up_p(r), cd_p(r), msg_p(r + 1),
                                           rs_b + (size_t)r * 64, up_b + (size_t)r * 64,
                                           cd_b + (size_t)r * 64, msg_b + (size_t)(r + 1) * 64,
                                           state_f, mout);
    else
      fused_rcm<1><<<GB, 256, 0, stream>>>(state_f, agg_h,
                                           rs_p(r), up_p(r), cd_p(r), nullptr,
                                           rs_b + (size_t)r * 64, up_b + (size_t)r * 64,
                                           cd_b + (size_t)r * 64, nullptr,
                                           out, nullptr);
  }
}